// Round 1
// baseline (1491.766 us; speedup 1.0000x reference)
//
#include <hip/hip_runtime.h>

#define Bv 4
#define Lv 1024
#define Ev 256
#define Hv 8
#define DHv 32

// ---------------------------------------------------------------------------
// GEMM: C[4096 x 256] = A[4096 x 256] @ W[256 x 256]^T + bias
// Used for Q/K/V projections and the final output projection.
// grid = (64, 4), block = 256. Each block: 64 rows x 64 cols, 4x4 per thread.
// LDS tiles stored transposed [kk][r] (pad 68) so compute reads are float4.
// ---------------------------------------------------------------------------
__global__ __launch_bounds__(256) void gemm_nt_256(const float* __restrict__ A,
                                                   const float* __restrict__ W,
                                                   const float* __restrict__ bias,
                                                   float* __restrict__ C) {
    __shared__ float Xs[32][68];
    __shared__ float Ws[32][68];
    const int row0 = blockIdx.x * 64;
    const int col0 = blockIdx.y * 64;
    const int t = threadIdx.x;
    const int tx = t & 15, ty = t >> 4;

    float acc[4][4] = {};

    for (int k0 = 0; k0 < 256; k0 += 32) {
        // stage 64x32 tiles of A-rows and W-rows (both accessed along k)
        #pragma unroll
        for (int q = 0; q < 8; ++q) {
            const int idx = t + q * 256;
            const int r = idx >> 5, kk = idx & 31;
            Xs[kk][r] = A[(size_t)(row0 + r) * 256 + k0 + kk];
            Ws[kk][r] = W[(size_t)(col0 + r) * 256 + k0 + kk];
        }
        __syncthreads();

        #pragma unroll
        for (int kk = 0; kk < 32; ++kk) {
            const float4 a4 = *(const float4*)&Xs[kk][ty * 4];
            const float4 b4 = *(const float4*)&Ws[kk][tx * 4];
            const float aa[4] = {a4.x, a4.y, a4.z, a4.w};
            const float bb[4] = {b4.x, b4.y, b4.z, b4.w};
            #pragma unroll
            for (int ri = 0; ri < 4; ++ri)
                #pragma unroll
                for (int ci = 0; ci < 4; ++ci)
                    acc[ri][ci] = fmaf(aa[ri], bb[ci], acc[ri][ci]);
        }
        __syncthreads();
    }

    #pragma unroll
    for (int ri = 0; ri < 4; ++ri) {
        const int row = row0 + ty * 4 + ri;
        #pragma unroll
        for (int ci = 0; ci < 4; ++ci) {
            const int col = col0 + tx * 4 + ci;
            C[(size_t)row * 256 + col] = acc[ri][ci] + bias[col];
        }
    }
}

// ---------------------------------------------------------------------------
// Attention: one block per (b, n). 256 threads.
//  scores[h][m] = (Q[b,n,h*32+:] . (K[b,m,h*32+:] )) + (Q[b,n,h*32+:] . KE[b,n,m,:])
//  (Q pre-scaled by 1/sqrt(E)); mask with -1e30; softmax per (h) row; P @ V.
// Each K row (1KB) and KE vector (128B) read exactly once per block.
// ---------------------------------------------------------------------------
__global__ __launch_bounds__(256) void attn_kernel(const float* __restrict__ Qb,
                                                   const float* __restrict__ Kb,
                                                   const float* __restrict__ Vb,
                                                   const int* __restrict__ adj,
                                                   const float* __restrict__ KE,
                                                   float* __restrict__ AT) {
    __shared__ __align__(16) float S[Hv][Lv];   // 32 KB score/prob matrix
    __shared__ __align__(16) float Qs[Ev];      // scaled query row

    const int bid = blockIdx.x;
    const int b = bid >> 10;
    const int n = bid & 1023;
    const int t = threadIdx.x;

    // 1. load Q row, pre-apply 1/sqrt(E) = 1/16
    Qs[t] = Qb[(size_t)(b * Lv + n) * Ev + t] * 0.0625f;
    __syncthreads();

    // 2. scores: thread t owns m = t, t+256, t+512, t+768 (all 8 heads each)
    const float4* __restrict__ K4 = (const float4*)Kb;
    const float4* __restrict__ KE4 = (const float4*)KE;
    const float4* __restrict__ Q4 = (const float4*)Qs;
    const size_t nrow = (size_t)(b * Lv + n) * Lv;   // base of adj / KE rows

    for (int j = 0; j < 4; ++j) {
        const int m = t + 256 * j;
        const int av = adj[nrow + m];

        // edge-feature vector for (b, n, m): 32 floats, reused by all 8 heads
        float4 ke[8];
        const float4* kep = KE4 + (nrow + m) * 8;
        #pragma unroll
        for (int q = 0; q < 8; ++q) ke[q] = kep[q];

        float acc[8] = {0.f, 0.f, 0.f, 0.f, 0.f, 0.f, 0.f, 0.f};
        const float4* krow = K4 + (size_t)(b * Lv + m) * 64;
        #pragma unroll
        for (int e4 = 0; e4 < 64; ++e4) {
            const float4 kv = krow[e4];
            const float4 qv = Q4[e4];
            const float4 kf = ke[e4 & 7];
            const int h = e4 >> 3;
            acc[h] = fmaf(qv.x, kv.x + kf.x, acc[h]);
            acc[h] = fmaf(qv.y, kv.y + kf.y, acc[h]);
            acc[h] = fmaf(qv.z, kv.z + kf.z, acc[h]);
            acc[h] = fmaf(qv.w, kv.w + kf.w, acc[h]);
        }
        #pragma unroll
        for (int h = 0; h < 8; ++h) S[h][m] = av ? acc[h] : -1e30f;
    }
    __syncthreads();

    // 3. softmax per head row: 32 threads per head (t>>5 = h, t&31 = lane d)
    float rowsum;
    {
        const int h = t >> 5, d = t & 31;
        float mx = -1e30f;
        #pragma unroll 8
        for (int jj = 0; jj < 32; ++jj) mx = fmaxf(mx, S[h][d + 32 * jj]);
        #pragma unroll
        for (int off = 16; off >= 1; off >>= 1)
            mx = fmaxf(mx, __shfl_xor(mx, off, 64));   // stays within 32-lane half

        float sum = 0.f;
        #pragma unroll 8
        for (int jj = 0; jj < 32; ++jj) {
            const int m = d + 32 * jj;
            const float p = __expf(S[h][m] - mx);      // masked: exp(-1e30-mx) -> 0
            S[h][m] = p;
            sum += p;
        }
        #pragma unroll
        for (int off = 16; off >= 1; off >>= 1)
            sum += __shfl_xor(sum, off, 64);
        rowsum = sum;   // all 32 lanes of the group hold it; >0 (self-loop)
    }
    __syncthreads();

    // 4. PV: thread t owns output column e = t (h = e>>5, d = e&31)
    {
        const int e = t;
        const int h = t >> 5;
        const float inv = 1.0f / rowsum;
        float acc = 0.f;
        const float4* S4 = (const float4*)&S[h][0];
        const float* vb = Vb + (size_t)(b * Lv) * Ev + e;
        for (int m4 = 0; m4 < 256; ++m4) {
            const float4 p = S4[m4];
            const float* vp = vb + (size_t)(m4 * 4) * Ev;
            acc = fmaf(p.x, vp[0],       acc);
            acc = fmaf(p.y, vp[Ev],      acc);
            acc = fmaf(p.z, vp[2 * Ev],  acc);
            acc = fmaf(p.w, vp[3 * Ev],  acc);
        }
        AT[(size_t)(b * Lv + n) * Ev + e] = acc * inv;
    }
}

// ---------------------------------------------------------------------------
extern "C" void kernel_launch(void* const* d_in, const int* in_sizes, int n_in,
                              void* d_out, int out_size, void* d_ws, size_t ws_size,
                              hipStream_t stream) {
    const float* X   = (const float*)d_in[0];
    const int*   adj = (const int*)d_in[1];
    const float* KE  = (const float*)d_in[2];
    const float* Wq  = (const float*)d_in[3];
    const float* bq  = (const float*)d_in[4];
    const float* Wk  = (const float*)d_in[5];
    const float* bk  = (const float*)d_in[6];
    const float* Wv  = (const float*)d_in[7];
    const float* bv  = (const float*)d_in[8];
    const float* Wo  = (const float*)d_in[9];
    const float* bo  = (const float*)d_in[10];

    const size_t NE = (size_t)Bv * Lv * Ev;   // 1M floats = 4MB
    float* Qb = (float*)d_ws;
    float* Kb = Qb + NE;
    float* Vb = Kb + NE;
    float* AT = Vb + NE;
    float* out = (float*)d_out;

    const dim3 blk(256);
    const dim3 gg(64, 4);

    hipLaunchKernelGGL(gemm_nt_256, gg, blk, 0, stream, X, Wq, bq, Qb);
    hipLaunchKernelGGL(gemm_nt_256, gg, blk, 0, stream, X, Wk, bk, Kb);
    hipLaunchKernelGGL(gemm_nt_256, gg, blk, 0, stream, X, Wv, bv, Vb);
    hipLaunchKernelGGL(attn_kernel, dim3(Bv * Lv), blk, 0, stream, Qb, Kb, Vb, adj, KE, AT);
    hipLaunchKernelGGL(gemm_nt_256, gg, blk, 0, stream, AT, Wo, bo, out);
}

// Round 2
// 723.396 us; speedup vs baseline: 2.0622x; 2.0622x over previous
//
#include <hip/hip_runtime.h>

#define Bv 4
#define Lv 1024
#define Ev 256
#define Hv 8
#define DHv 32

// ---------------------------------------------------------------------------
// GEMM: C[r0:r0+32, c0:c0+64] = A @ W^T + b, for one of up to 3 weight sets.
// blockIdx.x = row tile (4096/32 = 128); blockIdx.y = g*4 + coltile.
// 256 threads, 2x4 micro-tile. LDS tiles transposed [k][r] for vector reads.
// ---------------------------------------------------------------------------
__global__ __launch_bounds__(256) void gemm_fused(
    const float* __restrict__ A,
    const float* __restrict__ W0, const float* __restrict__ b0, float* __restrict__ C0,
    const float* __restrict__ W1, const float* __restrict__ b1, float* __restrict__ C1,
    const float* __restrict__ W2, const float* __restrict__ b2, float* __restrict__ C2) {
    __shared__ float Xs[32][34];
    __shared__ float Ws[32][68];
    const int g = blockIdx.y >> 2;
    const float* __restrict__ W    = (g == 0) ? W0 : (g == 1) ? W1 : W2;
    const float* __restrict__ bias = (g == 0) ? b0 : (g == 1) ? b1 : b2;
    float* __restrict__ C          = (g == 0) ? C0 : (g == 1) ? C1 : C2;

    const int row0 = blockIdx.x * 32;
    const int col0 = (blockIdx.y & 3) * 64;
    const int t = threadIdx.x;
    const int tx = t & 15, ty = t >> 4;
    const int lr = t >> 3, lk = (t & 7) * 4;

    float acc[2][4] = {};

    for (int k0 = 0; k0 < 256; k0 += 32) {
        const float4 av = *(const float4*)&A[(size_t)(row0 + lr) * 256 + k0 + lk];
        const float4 w0 = *(const float4*)&W[(size_t)(col0 + lr) * 256 + k0 + lk];
        const float4 w1 = *(const float4*)&W[(size_t)(col0 + 32 + lr) * 256 + k0 + lk];
        Xs[lk + 0][lr] = av.x; Xs[lk + 1][lr] = av.y;
        Xs[lk + 2][lr] = av.z; Xs[lk + 3][lr] = av.w;
        Ws[lk + 0][lr] = w0.x; Ws[lk + 1][lr] = w0.y;
        Ws[lk + 2][lr] = w0.z; Ws[lk + 3][lr] = w0.w;
        Ws[lk + 0][32 + lr] = w1.x; Ws[lk + 1][32 + lr] = w1.y;
        Ws[lk + 2][32 + lr] = w1.z; Ws[lk + 3][32 + lr] = w1.w;
        __syncthreads();

        #pragma unroll
        for (int kk = 0; kk < 32; ++kk) {
            const float2 a2 = *(const float2*)&Xs[kk][ty * 2];
            const float4 b4 = *(const float4*)&Ws[kk][tx * 4];
            acc[0][0] = fmaf(a2.x, b4.x, acc[0][0]);
            acc[0][1] = fmaf(a2.x, b4.y, acc[0][1]);
            acc[0][2] = fmaf(a2.x, b4.z, acc[0][2]);
            acc[0][3] = fmaf(a2.x, b4.w, acc[0][3]);
            acc[1][0] = fmaf(a2.y, b4.x, acc[1][0]);
            acc[1][1] = fmaf(a2.y, b4.y, acc[1][1]);
            acc[1][2] = fmaf(a2.y, b4.z, acc[1][2]);
            acc[1][3] = fmaf(a2.y, b4.w, acc[1][3]);
        }
        __syncthreads();
    }

    const float4 bv4 = *(const float4*)&bias[col0 + tx * 4];
    #pragma unroll
    for (int ri = 0; ri < 2; ++ri) {
        const int row = row0 + ty * 2 + ri;
        float4 o;
        o.x = acc[ri][0] + bv4.x; o.y = acc[ri][1] + bv4.y;
        o.z = acc[ri][2] + bv4.z; o.w = acc[ri][3] + bv4.w;
        *(float4*)&C[(size_t)row * 256 + col0 + tx * 4] = o;
    }
}

// ---------------------------------------------------------------------------
// Sparse attention: one block per (b, n), 256 threads.
// adj is ~5% dense; only active m's get scores / KE loads / PV terms.
// Processed in 4 chunks of 256 m with online softmax (robust to any density).
// ---------------------------------------------------------------------------
__global__ __launch_bounds__(256) void attn_sparse(const float* __restrict__ Qb,
                                                   const float* __restrict__ Kb,
                                                   const float* __restrict__ Vb,
                                                   const int* __restrict__ adj,
                                                   const float* __restrict__ KE,
                                                   float* __restrict__ AT) {
    __shared__ __align__(16) float Qs[Ev];      // scaled query row
    __shared__ __align__(16) float S[Hv][260];  // chunk scores -> probs
    __shared__ int idxm[256];                   // active m's in this chunk
    __shared__ int cntS;
    __shared__ float mh[Hv], lh[Hv], scaleh[Hv];

    const int bid = blockIdx.x;
    const int b = bid >> 10;
    const int n = bid & 1023;
    const int t = threadIdx.x;
    const int lane = t & 63;
    const int h_of_t = t >> 5;                  // output head for e = t
    const size_t nrow = (size_t)(b * Lv + n) * Lv;

    Qs[t] = Qb[(size_t)(b * Lv + n) * Ev + t] * 0.0625f;   // 1/sqrt(256)
    if (t < Hv) { mh[t] = -1e30f; lh[t] = 0.f; }

    float acc = 0.f;   // output element e = t
    const float* __restrict__ vcol = Vb + (size_t)b * Lv * Ev + t;
    const float4* __restrict__ K4 = (const float4*)Kb;
    const float4* __restrict__ KE4 = (const float4*)KE;
    const float4* __restrict__ Q4 = (const float4*)Qs;

    for (int c = 0; c < 4; ++c) {
        if (t == 0) cntS = 0;
        __syncthreads();

        // --- compaction of active m's (wave ballot + LDS base) ---
        const int m = c * 256 + t;
        const bool p = adj[nrow + m] != 0;
        const unsigned long long mask = __ballot(p);
        const int prefix = __popcll(mask & ((1ull << lane) - 1ull));
        int base = 0;
        if (lane == 0) base = atomicAdd(&cntS, __popcll(mask));
        base = __shfl(base, 0, 64);
        if (p) idxm[base + prefix] = m;
        __syncthreads();

        const int cnt = cntS;

        // --- scores for (entry, head) tasks ---
        for (int tb = 0; tb < cnt * 8; tb += 256) {
            const int task = tb + t;
            if (task < cnt * 8) {
                const int ei = task >> 3, h = task & 7;
                const int mm = idxm[ei];
                const float4* kp = K4 + (size_t)(b * Lv + mm) * 64 + h * 8;
                const float4* kep = KE4 + (nrow + mm) * 8;
                const float4* qp = Q4 + h * 8;
                float dot = 0.f;
                #pragma unroll
                for (int j = 0; j < 8; ++j) {
                    const float4 kv = kp[j], kf = kep[j], qv = qp[j];
                    dot = fmaf(qv.x, kv.x + kf.x, dot);
                    dot = fmaf(qv.y, kv.y + kf.y, dot);
                    dot = fmaf(qv.z, kv.z + kf.z, dot);
                    dot = fmaf(qv.w, kv.w + kf.w, dot);
                }
                S[h][ei] = dot;
            }
        }
        __syncthreads();

        // --- online softmax merge: 32 threads per head ---
        {
            const int h = t >> 5, d = t & 31;
            float cmax = -1e30f;
            for (int i = d; i < cnt; i += 32) cmax = fmaxf(cmax, S[h][i]);
            #pragma unroll
            for (int off = 16; off >= 1; off >>= 1)
                cmax = fmaxf(cmax, __shfl_xor(cmax, off, 64));
            const float oldm = mh[h];
            const float newm = fmaxf(oldm, cmax);
            float csum = 0.f;
            for (int i = d; i < cnt; i += 32) {
                const float pz = __expf(S[h][i] - newm);
                S[h][i] = pz;
                csum += pz;
            }
            #pragma unroll
            for (int off = 16; off >= 1; off >>= 1)
                csum += __shfl_xor(csum, off, 64);
            if (d == 0) {
                const float sc = __expf(oldm - newm);
                scaleh[h] = sc;
                lh[h] = lh[h] * sc + csum;
                mh[h] = newm;
            }
        }
        __syncthreads();

        // --- PV accumulate: thread t owns output element e = t ---
        {
            acc *= scaleh[h_of_t];
            int i = 0;
            for (; i + 4 <= cnt; i += 4) {
                const int m0 = idxm[i], m1 = idxm[i + 1], m2 = idxm[i + 2], m3 = idxm[i + 3];
                const float p0 = S[h_of_t][i],     p1 = S[h_of_t][i + 1];
                const float p2 = S[h_of_t][i + 2], p3 = S[h_of_t][i + 3];
                const float v0 = vcol[(size_t)m0 * Ev];
                const float v1 = vcol[(size_t)m1 * Ev];
                const float v2 = vcol[(size_t)m2 * Ev];
                const float v3 = vcol[(size_t)m3 * Ev];
                acc = fmaf(p0, v0, acc);
                acc = fmaf(p1, v1, acc);
                acc = fmaf(p2, v2, acc);
                acc = fmaf(p3, v3, acc);
            }
            for (; i < cnt; ++i)
                acc = fmaf(S[h_of_t][i], vcol[(size_t)idxm[i] * Ev], acc);
        }
        __syncthreads();
    }

    AT[(size_t)(b * Lv + n) * Ev + t] = acc / lh[h_of_t];
}

// ---------------------------------------------------------------------------
extern "C" void kernel_launch(void* const* d_in, const int* in_sizes, int n_in,
                              void* d_out, int out_size, void* d_ws, size_t ws_size,
                              hipStream_t stream) {
    const float* X   = (const float*)d_in[0];
    const int*   adj = (const int*)d_in[1];
    const float* KE  = (const float*)d_in[2];
    const float* Wq  = (const float*)d_in[3];
    const float* bq  = (const float*)d_in[4];
    const float* Wk  = (const float*)d_in[5];
    const float* bk  = (const float*)d_in[6];
    const float* Wv  = (const float*)d_in[7];
    const float* bv  = (const float*)d_in[8];
    const float* Wo  = (const float*)d_in[9];
    const float* bo  = (const float*)d_in[10];

    const size_t NE = (size_t)Bv * Lv * Ev;   // 1M floats = 4MB
    float* Qb = (float*)d_ws;
    float* Kb = Qb + NE;
    float* Vb = Kb + NE;
    float* AT = Vb + NE;
    float* out = (float*)d_out;

    const dim3 blk(256);

    // fused Q/K/V projections: 128 row-tiles x (3 mats x 4 col-tiles)
    hipLaunchKernelGGL(gemm_fused, dim3(128, 12), blk, 0, stream, X,
                       Wq, bq, Qb, Wk, bk, Kb, Wv, bv, Vb);
    hipLaunchKernelGGL(attn_sparse, dim3(Bv * Lv), blk, 0, stream,
                       Qb, Kb, Vb, adj, KE, AT);
    // output projection (g is always 0)
    hipLaunchKernelGGL(gemm_fused, dim3(128, 4), blk, 0, stream, AT,
                       Wo, bo, out, Wo, bo, out, Wo, bo, out);
}